// Round 8
// baseline (892.931 us; speedup 1.0000x reference)
//
#include <hip/hip_runtime.h>

#define HW 128
#define COUTC 512
#define NB 4097
#define NSEL 300
#define T_TOP 4096
#define TW 64           // words per mask row = T_TOP/64
#define FAST_N 1024

typedef _Float16 half8 __attribute__((ext_vector_type(8)));
typedef _Float16 half4v __attribute__((ext_vector_type(4)));
typedef float floatx4 __attribute__((ext_vector_type(4)));

// ================= fast-path ws layout (bytes) =================
#define NWS_A1H   ((size_t)0)            // 34,611,200  (dead after conv1 -> MSK 2MB)
#define NWS_A1L   ((size_t)34611200)     // (dead after conv1 -> CBOX/CAREA)
#define NWS_W1H   ((size_t)69222400)
#define NWS_W1L   ((size_t)78659584)
#define NWS_A2H   ((size_t)88096768)
#define NWS_A2L   ((size_t)105402368)
#define NWS_W2H   ((size_t)122707968)
#define NWS_W2L   ((size_t)127426560)
#define NWS_X2    ((size_t)132145152)    // xh (16,777,216) + xl (16,777,216)
#define NWS_BOXES ((size_t)165699584)
#define NWS_KEYS  ((size_t)168058880)    // reused as sorted keys (sk2)
#define NWS_SKEYS ((size_t)169238528)    // wbh/wbl live here until heads done
#define NWS_HIST  ((size_t)170418176)
#define NWS_CUR   ((size_t)170434816)
#define NWS_CNT   ((size_t)170451456)
#define NWS_BASE  ((size_t)170451712)
#define NWS_TOTAL ((size_t)170468352)

// ================= fallback ws layout =================
#define WS_X1     ((size_t)0)
#define WS_X2     ((size_t)33554432)
#define WS_BOXES  ((size_t)67108864)
#define WS_KEYS   ((size_t)69468160)
#define WS_SKEYS  ((size_t)70647808)
#define WS_HIST   ((size_t)71827456)
#define WS_CUR    ((size_t)71844096)
#define WS_CNT    ((size_t)71860736)
#define WS_BASE   ((size_t)71860992)

__device__ __forceinline__ void glds16(const void* g, void* l) {
    __builtin_amdgcn_global_load_lds(
        (const __attribute__((address_space(1))) void*)g,
        (__attribute__((address_space(3))) void*)l, 16, 0, 0);
}

// Activation layout (per padded row pr): [chunk(CIN/32)][sub(4)][pc(130)][8ch]
// Weight layout (per tap): [chunk(CIN/32)][sub(4)][oc(512)][8ch]
// conv2-output (heads input) layout (per row h): [chunk(16)][sub(4)][pix(128)][8ch], rowstride 65536 halves

// ---------------- weight convert body ----------------
template<int CIN>
__device__ __forceinline__ void convert_w_body(
    int b, const float* __restrict__ w, _Float16* __restrict__ wh, _Float16* __restrict__ wl)
{
    constexpr int NU = CIN / 8;
    int gid = b * 256 + threadIdx.x;
    int oc = gid & 511;
    int rest = gid >> 9;
    int u = rest & (NU - 1);
    int tap = rest / NU;
    if (tap >= 9) return;
    int k0 = u * 8;
    half8 vh, vl;
    #pragma unroll
    for (int j = 0; j < 8; ++j) {
        float v = w[((size_t)tap * CIN + k0 + j) * 512 + oc] * 64.f;
        _Float16 hi = (_Float16)v;
        vh[j] = hi;
        vl[j] = (_Float16)(v - (float)hi);
    }
    size_t o = (size_t)tap * CIN * 512 + (size_t)(k0 >> 5) * 16384
             + (size_t)((k0 >> 3) & 3) * 4096 + (size_t)oc * 8;
    *(half8*)(wh + o) = vh;
    *(half8*)(wl + o) = vl;
}

// ---------------- fused front-end: feature convert + all weight prep + hist/cur/cnt zero -----
__global__ __launch_bounds__(256) void fused_prep_kernel(
    const float* __restrict__ feat, _Float16* __restrict__ ah, _Float16* __restrict__ al,
    const float* __restrict__ w1, _Float16* __restrict__ w1h, _Float16* __restrict__ w1l,
    const float* __restrict__ w2, _Float16* __restrict__ w2h, _Float16* __restrict__ w2l,
    const float* __restrict__ w_s, const float* __restrict__ w_b,
    _Float16* __restrict__ wbh, _Float16* __restrict__ wbl,
    _Float16* __restrict__ a2h, _Float16* __restrict__ a2l,
    int4* __restrict__ zeros)
{
    __shared__ __align__(16) _Float16 lh[130 * 32];
    __shared__ __align__(16) _Float16 ll[130 * 32];
    int b = blockIdx.x;
    if (b < 4160) {      // ---- feature convert: LDS transpose, coalesced both ways ----
        int pr = b % 130;        // 0..129
        int chunk = b / 130;     // 0..31
        int t = threadIdx.x;
        int c  = t & 31;
        int pg = t >> 5;         // 0..7
        bool interior = (pr >= 1 && pr <= 128);
        if (interior) {
            for (int px = pg; px < 128; px += 8) {
                float x = feat[((size_t)(pr - 1) * 128 + px) * 1024 + chunk * 32 + c];
                x = fmaxf(x, 0.f);
                _Float16 hi = (_Float16)x;
                lh[(px + 1) * 32 + c] = hi;
                ll[(px + 1) * 32 + c] = (_Float16)(x - (float)hi);
            }
        } else {
            for (int px = pg; px < 128; px += 8) {
                lh[(px + 1) * 32 + c] = (_Float16)0.f;
                ll[(px + 1) * 32 + c] = (_Float16)0.f;
            }
        }
        if (t < 32) {
            lh[t] = (_Float16)0.f;          ll[t] = (_Float16)0.f;
            lh[129 * 32 + t] = (_Float16)0.f; ll[129 * 32 + t] = (_Float16)0.f;
        }
        __syncthreads();
        size_t base = (size_t)pr * 133120 + (size_t)chunk * 4160;
        for (int i = t; i < 520; i += 256) {
            int sub = i / 130;
            int pc  = i - sub * 130;
            *(float4*)&ah[base + sub * 1040 + pc * 8] = *(const float4*)&lh[pc * 32 + sub * 8];
            *(float4*)&al[base + sub * 1040 + pc * 8] = *(const float4*)&ll[pc * 32 + sub * 8];
        }
        return;
    }
    b -= 4160;
    if (b < 2304) { convert_w_body<1024>(b, w1, w1h, w1l); return; }
    if (b < 3456) { convert_w_body<512>(b - 2304, w2, w2h, w2l); return; }
    if (b < 3584) {      // ---- head weights: 32768 = 64n x 512k ----
        int gid = (b - 3456) * 256 + threadIdx.x;
        int n = gid & 63;
        int k = gid >> 6;
        float v = 0.f;
        if (n < 9)       v = w_s[k * 9 + n] * 64.f;
        else if (n < 45) v = w_b[k * 36 + (n - 9)] * 64.f;
        _Float16 hi = (_Float16)v;
        size_t o = (size_t)(k >> 5) * 2048 + (size_t)((k >> 3) & 3) * 512 + (size_t)n * 8 + (k & 7);
        wbh[o] = hi;
        wbl[o] = (_Float16)(v - (float)hi);
        return;
    }
    if (b < 4100) {      // ---- a2 pad ring (516 blocks) ----
        int i = b - 3584;
        int pr, pc;
        if (i < 130)      { pr = 0;        pc = i; }
        else if (i < 260) { pr = 129;      pc = i - 130; }
        else if (i < 388) { pr = i - 259;  pc = 0; }
        else              { pr = i - 387;  pc = 129; }
        int t = threadIdx.x;
        if (t >= 128) return;
        _Float16* dst = (t & 64) ? a2l : a2h;
        int u = t & 63;
        size_t o = (size_t)pr * 66560 + (size_t)(u >> 2) * 4160 + (size_t)(u & 3) * 1040 + (size_t)pc * 8;
        *(float4*)(dst + o) = make_float4(0.f, 0.f, 0.f, 0.f);
        return;
    }
    {                    // ---- hist/cur/cnt zero: 33536 B = 2096 int4 (9 blocks) ----
        int gid = (b - 4100) * 256 + threadIdx.x;
        if (gid < 2096) zeros[gid] = make_int4(0, 0, 0, 0);
    }
}

// ---------------- conv 3x3 fp16-split MFMA, 128x128 tile, BK=64, 512-thread, B-in-registers --
// Round-7 structure for A (glds stage + __syncthreads lockstep -- DO NOT change: rounds 1/5/6
// showed any drain/choreography change inflates FETCH 1.6-3x). B (weights) now loads DIRECTLY
// into MFMA operand registers (per-lane contiguous 16B, fully coalesced): glds/thread 8->4,
// ds_reads/slice 12->8, LDS 64KB->32KB. B loads issue before the same __syncthreads and are
// drained by the same vmcnt(0) -- synchronization semantics identical. B is XCD-shared weights
// (18.9MB) so no FETCH inflation possible. Per-accumulator FP sequence (tap -> kc32 ->
// hh,hl,lh) IDENTICAL: bit-exact outputs.
template<int CIN, bool PAD>
__global__ __launch_bounds__(512, 4) void conv_mfma_kernel(
    const _Float16* __restrict__ ah, const _Float16* __restrict__ al,
    const _Float16* __restrict__ wh, const _Float16* __restrict__ wl,
    const float* __restrict__ bias,
    _Float16* __restrict__ oh, _Float16* __restrict__ ol)
{
    constexpr int ROWSTR = CIN * 130;
    constexpr int TAPW   = CIN * 512;
    __shared__ __align__(16) _Float16 lds[16384];   // A only: [s(2)][h/l via +8192][wave*512]

    int bx = blockIdx.x;          // grid 512: bx%8 == h%8 (baseline XCD choreography)
    int h  = bx & 127;
    int n0 = (bx >> 7) << 7;

    int tid  = threadIdx.x;
    int wave = tid >> 6;          // 0..7
    int lane = tid & 63;
    int fr = lane & 15;
    int fq = lane >> 4;

    int aoff0 = fq * 1040 + (16 * wave + fr) * 8;
    int wm = wave & 1, wn = wave >> 1;   // wn 0..3
    int bofr = fq * 4096 + (n0 + wn * 32 + fr) * 8;   // B fragment base (j adds 128 halves)

    floatx4 acc[4][2];
    #pragma unroll
    for (int i = 0; i < 4; ++i)
        #pragma unroll
        for (int j = 0; j < 2; ++j)
            acc[i][j] = (floatx4){0.f, 0.f, 0.f, 0.f};

    #pragma unroll
    for (int tap = 0; tap < 9; ++tap) {
        int dy = tap / 3 - 1, dx = tap % 3 - 1;
        const _Float16* gAh = ah + (size_t)(h + dy + 1) * ROWSTR + (dx + 1) * 8;
        const _Float16* gAl = al + (size_t)(h + dy + 1) * ROWSTR + (dx + 1) * 8;
        const _Float16* gBh = wh + (size_t)tap * TAPW;
        const _Float16* gBl = wl + (size_t)tap * TAPW;

        for (int kc = 0; kc < CIN; kc += 64) {
            // stage A (4 glds/thread)
            #pragma unroll
            for (int s = 0; s < 2; ++s) {
                int ab = ((kc >> 5) + s) * 4160;
                glds16(gAh + ab + aoff0, lds +        s * 4096 + wave * 512);
                glds16(gAl + ab + aoff0, lds + 8192 + s * 4096 + wave * 512);
            }
            // B fragments direct to registers (8 dwordx4 loads/thread, coalesced)
            half8 cbh[2][2], cbl[2][2];
            #pragma unroll
            for (int s = 0; s < 2; ++s) {
                int bb = ((kc >> 5) + s) * 16384;
                #pragma unroll
                for (int j = 0; j < 2; ++j) {
                    cbh[s][j] = *(const half8*)(gBh + bb + bofr + j * 128);
                    cbl[s][j] = *(const half8*)(gBl + bb + bofr + j * 128);
                }
            }
            __syncthreads();

            #pragma unroll
            for (int s = 0; s < 2; ++s) {
                const _Float16* rAh = lds + s * 4096 + wm * 2048 + fq * 128 + fr * 8;
                const _Float16* rAl = rAh + 8192;

                half8 fah[4], fal[4];
                #pragma unroll
                for (int i = 0; i < 4; ++i) {
                    fah[i] = *(const half8*)(rAh + i * 512);
                    fal[i] = *(const half8*)(rAl + i * 512);
                }
                #pragma unroll
                for (int i = 0; i < 4; ++i)
                    #pragma unroll
                    for (int j = 0; j < 2; ++j)
                        acc[i][j] = __builtin_amdgcn_mfma_f32_16x16x32_f16(fah[i], cbh[s][j], acc[i][j], 0, 0, 0);
                #pragma unroll
                for (int i = 0; i < 4; ++i)
                    #pragma unroll
                    for (int j = 0; j < 2; ++j)
                        acc[i][j] = __builtin_amdgcn_mfma_f32_16x16x32_f16(fah[i], cbl[s][j], acc[i][j], 0, 0, 0);
                #pragma unroll
                for (int i = 0; i < 4; ++i)
                    #pragma unroll
                    for (int j = 0; j < 2; ++j)
                        acc[i][j] = __builtin_amdgcn_mfma_f32_16x16x32_f16(fal[i], cbh[s][j], acc[i][j], 0, 0, 0);
            }
            __syncthreads();
        }
    }

    const float scale = 1.f / 64.f;
    int em = 64 * wm + fq * 4;
    int en = 32 * wn + fr;
    #pragma unroll
    for (int j = 0; j < 2; ++j) {
        int oc = n0 + en + 16 * j;
        float b2 = bias[oc];
        #pragma unroll
        for (int i = 0; i < 4; ++i) {
            #pragma unroll
            for (int r = 0; r < 4; ++r) {
                int w = em + 16 * i + r;
                float v = fmaf(acc[i][j][r], scale, b2);
                if (PAD) {
                    v = fmaxf(v, 0.f);
                    _Float16 hi = (_Float16)v;
                    size_t o = (size_t)(h + 1) * 66560 + (size_t)(oc >> 5) * 4160
                             + (size_t)((oc >> 3) & 3) * 1040 + (size_t)(w + 1) * 8 + (oc & 7);
                    oh[o] = hi;
                    ol[o] = (_Float16)(v - (float)hi);
                } else {
                    _Float16 hi = (_Float16)v;
                    size_t o = (size_t)h * 65536 + (size_t)(oc >> 5) * 4096
                             + (size_t)((oc >> 3) & 3) * 1024 + (size_t)w * 8 + (oc & 7);
                    oh[o] = hi;
                    ol[o] = (_Float16)(v - (float)hi);
                }
            }
        }
    }
}

// ---------------- decode helper ----------------
__device__ __forceinline__ void decode_emit(
    int gi, float z, float dyv, float dxv, float dhv, float dwv,
    float4* __restrict__ boxes, unsigned long long* __restrict__ keys,
    int* __restrict__ cnt, int* __restrict__ hist)
{
    int a = gi % 9;
    int pix = gi / 9;
    int h = pix >> 7, w = pix & 127;
    float sc  = (a < 3) ? 128.f : ((a < 6) ? 256.f : 512.f);
    int r = a - (a / 3) * 3;
    float ratio = (r == 0) ? 0.5f : ((r == 1) ? 1.f : 2.f);
    float sr = sqrtf(ratio);
    float ahh = sc * sr, aww = sc / sr;
    float acy = ((float)h + 0.5f) * 16.f;
    float acx = ((float)w + 0.5f) * 16.f;
    float cy = fmaf(dyv, ahh, acy);
    float cx = fmaf(dxv, aww, acx);
    float hh = ahh * expf(dhv);
    float ww = aww * expf(dwv);
    float y1 = fminf(fmaxf(cy - 0.5f * hh, 0.f), 2048.f);
    float x1 = fminf(fmaxf(cx - 0.5f * ww, 0.f), 2048.f);
    float y2 = fminf(fmaxf(cy + 0.5f * hh, 0.f), 2048.f);
    float x2 = fminf(fmaxf(cx + 0.5f * ww, 0.f), 2048.f);
    boxes[gi] = make_float4(y1, x1, y2, x2);
    float s = 1.f / (1.f + expf(-z));
    if (s >= 0.5f) {
        unsigned u = __float_as_uint(s);
        unsigned d = 0x3F800000u - u;
        unsigned long long key = ((unsigned long long)d << 18) | (unsigned)gi;
        int p = atomicAdd(cnt, 1);
        keys[p] = key;
        atomicAdd(&hist[d >> 11], 1);
    }
}

// ---------------- heads via MFMA: 128 blocks, M=128 px, N=48(pad 64), K=512 ----------------
__global__ __launch_bounds__(256) void heads_mfma_kernel(
    const _Float16* __restrict__ xh, const _Float16* __restrict__ xl,
    const _Float16* __restrict__ wbh, const _Float16* __restrict__ wbl,
    const float* __restrict__ b_s, const float* __restrict__ b_b,
    float4* __restrict__ boxes, unsigned long long* __restrict__ keys,
    int* __restrict__ cnt, int* __restrict__ hist)
{
    __shared__ __align__(16) char smem[24576];
    _Float16* sAh = (_Float16*)smem;             // 4096 halves: [sub4][pix128][8]
    _Float16* sAl = (_Float16*)(smem + 8192);
    _Float16* sBh = (_Float16*)(smem + 16384);   // 2048 halves: [sub4][n64][8]
    _Float16* sBl = (_Float16*)(smem + 20480);
    float* outs = (float*)smem;                  // overlay after K-loop: [128][48] = 24576 B
    __shared__ float sb[48];

    int tid  = threadIdx.x;
    int wave = tid >> 6;
    int lane = tid & 63;
    int fr = lane & 15;
    int fq = lane >> 4;
    if (tid < 48) sb[tid] = (tid < 9) ? b_s[tid] : ((tid < 45) ? b_b[tid - 9] : 0.f);

    int h = blockIdx.x;
    int wm = wave & 1, wn = wave >> 1;

    floatx4 acc[4][2];
    #pragma unroll
    for (int i = 0; i < 4; ++i)
        #pragma unroll
        for (int j = 0; j < 2; ++j)
            acc[i][j] = (floatx4){0.f, 0.f, 0.f, 0.f};

    for (int kc = 0; kc < 16; ++kc) {
        const _Float16* gxh = xh + (size_t)h * 65536 + kc * 4096;
        const _Float16* gxl = xl + (size_t)h * 65536 + kc * 4096;
        glds16(gxh + tid * 8,        sAh + tid * 8);
        glds16(gxh + 2048 + tid * 8, sAh + 2048 + tid * 8);
        glds16(gxl + tid * 8,        sAl + tid * 8);
        glds16(gxl + 2048 + tid * 8, sAl + 2048 + tid * 8);
        glds16(wbh + kc * 2048 + tid * 8, sBh + tid * 8);
        glds16(wbl + kc * 2048 + tid * 8, sBl + tid * 8);
        __syncthreads();

        half8 fah[4], fal[4], fbh[2], fbl[2];
        #pragma unroll
        for (int i = 0; i < 4; ++i) {
            int px = wm * 64 + 16 * i + fr;
            int aaddr = fq * 1024 + px * 8;
            fah[i] = *(const half8*)(sAh + aaddr);
            fal[i] = *(const half8*)(sAl + aaddr);
        }
        #pragma unroll
        for (int j = 0; j < 2; ++j) {
            int n = wn * 32 + 16 * j + fr;
            int baddr = fq * 512 + n * 8;
            fbh[j] = *(const half8*)(sBh + baddr);
            fbl[j] = *(const half8*)(sBl + baddr);
        }
        #pragma unroll
        for (int i = 0; i < 4; ++i)
            #pragma unroll
            for (int j = 0; j < 2; ++j) {
                acc[i][j] = __builtin_amdgcn_mfma_f32_16x16x32_f16(fah[i], fbh[j], acc[i][j], 0, 0, 0);
                acc[i][j] = __builtin_amdgcn_mfma_f32_16x16x32_f16(fah[i], fbl[j], acc[i][j], 0, 0, 0);
                acc[i][j] = __builtin_amdgcn_mfma_f32_16x16x32_f16(fal[i], fbh[j], acc[i][j], 0, 0, 0);
            }
        __syncthreads();
    }

    const float scale = 1.f / 64.f;
    #pragma unroll
    for (int i = 0; i < 4; ++i)
        #pragma unroll
        for (int j = 0; j < 2; ++j)
            #pragma unroll
            for (int r = 0; r < 4; ++r) {
                int px = wm * 64 + 16 * i + fq * 4 + r;
                int n = wn * 32 + 16 * j + fr;
                if (n < 48)
                    outs[px * 48 + n] = fmaf(acc[i][j][r], scale, sb[n]);
            }
    __syncthreads();

    if (tid < 128) {
        int p = tid;
        #pragma unroll
        for (int a = 0; a < 9; ++a) {
            float z   = outs[p * 48 + a];
            float dyv = outs[p * 48 + 9 + 4 * a + 0];
            float dxv = outs[p * 48 + 9 + 4 * a + 1];
            float dhv = outs[p * 48 + 9 + 4 * a + 2];
            float dwv = outs[p * 48 + 9 + 4 * a + 3];
            int gi = (h * 128 + p) * 9 + a;
            decode_emit(gi, z, dyv, dxv, dhv, dwv, boxes, keys, cnt, hist);
        }
    }
}

// ---------------- fallback fp32 conv ----------------
template<int CIN, bool RELU_IN, bool RELU_OUT>
__global__ __launch_bounds__(256) void conv3x3_kernel(
    const float* __restrict__ in, const float* __restrict__ wgt,
    const float* __restrict__ bias, float* __restrict__ out)
{
    __shared__ float As[32][68];
    __shared__ float Bs[32][64];
    int bx = blockIdx.x;
    int mtile = bx & 255, ntile = bx >> 8;
    int h = mtile >> 1, w0 = (mtile & 1) << 6, n0 = ntile << 6;
    int tid = threadIdx.x, ty = tid >> 4, tx = tid & 15;
    float acc[4][4] = {{0.f}};
    const int KTOT = 9 * CIN;
    for (int k0 = 0; k0 < KTOT; k0 += 32) {
        int tap = k0 / CIN, icb = k0 % CIN;
        int dy = tap / 3 - 1, dx = tap % 3 - 1;
        int row = h + dy;
        bool rowok = ((unsigned)row < HW);
        {
            int pix = tid >> 3, cs = (tid & 7) << 2;
            #pragma unroll
            for (int p = 0; p < 2; ++p) {
                int px = pix + p * 32;
                int wcol = w0 + px + dx;
                float4 v = make_float4(0.f, 0.f, 0.f, 0.f);
                if (rowok && (unsigned)wcol < HW) {
                    v = *(const float4*)&in[((size_t)row * HW + wcol) * CIN + icb + cs];
                    if (RELU_IN) {
                        v.x = fmaxf(v.x, 0.f); v.y = fmaxf(v.y, 0.f);
                        v.z = fmaxf(v.z, 0.f); v.w = fmaxf(v.w, 0.f);
                    }
                }
                As[cs + 0][px] = v.x; As[cs + 1][px] = v.y;
                As[cs + 2][px] = v.z; As[cs + 3][px] = v.w;
            }
        }
        {
            int kr = tid >> 4, nc = (tid & 15) << 2;
            #pragma unroll
            for (int p = 0; p < 2; ++p) {
                int k = kr + p * 16;
                *(float4*)&Bs[k][nc] = *(const float4*)&wgt[(size_t)(k0 + k) * COUTC + n0 + nc];
            }
        }
        __syncthreads();
        #pragma unroll
        for (int kk = 0; kk < 32; ++kk) {
            float4 a = *(const float4*)&As[kk][ty << 2];
            float4 b = *(const float4*)&Bs[kk][tx << 2];
            float av[4] = {a.x, a.y, a.z, a.w};
            float bv[4] = {b.x, b.y, b.z, b.w};
            #pragma unroll
            for (int i = 0; i < 4; ++i)
                #pragma unroll
                for (int j = 0; j < 4; ++j)
                    acc[i][j] = fmaf(av[i], bv[j], acc[i][j]);
        }
        __syncthreads();
    }
    float4 bi = *(const float4*)&bias[n0 + (tx << 2)];
    float bv2[4] = {bi.x, bi.y, bi.z, bi.w};
    #pragma unroll
    for (int i = 0; i < 4; ++i) {
        float4 o;
        o.x = acc[i][0] + bv2[0]; o.y = acc[i][1] + bv2[1];
        o.z = acc[i][2] + bv2[2]; o.w = acc[i][3] + bv2[3];
        if (RELU_OUT) {
            o.x = fmaxf(o.x, 0.f); o.y = fmaxf(o.y, 0.f);
            o.z = fmaxf(o.z, 0.f); o.w = fmaxf(o.w, 0.f);
        }
        *(float4*)&out[((size_t)(h * HW) + w0 + (ty << 2) + i) * COUTC + n0 + (tx << 2)] = o;
    }
}

// ---------------- fallback heads ----------------
__global__ __launch_bounds__(256) void heads_decode_kernel(
    const float* __restrict__ x, const float* __restrict__ w_s, const float* __restrict__ b_s,
    const float* __restrict__ w_b, const float* __restrict__ b_b,
    float4* __restrict__ boxes, unsigned long long* __restrict__ keys,
    int* __restrict__ cnt, int* __restrict__ hist)
{
    __shared__ float xs[4][512];
    __shared__ float outs[4][45];
    int wave = threadIdx.x >> 6;
    int lane = threadIdx.x & 63;
    int pix  = blockIdx.x * 4 + wave;

    const float4* xp = (const float4*)&x[(size_t)pix * COUTC];
    *(float4*)&xs[wave][lane * 4]       = xp[lane];
    *(float4*)&xs[wave][256 + lane * 4] = xp[64 + lane];
    __syncthreads();

    if (lane < 45) {
        const float* wp; int stride; float acc;
        if (lane < 9) { wp = w_s + lane;       stride = 9;  acc = b_s[lane]; }
        else          { wp = w_b + (lane - 9); stride = 36; acc = b_b[lane - 9]; }
        const float* xrow = xs[wave];
        for (int k = 0; k < 512; k += 4) {
            acc = fmaf(xrow[k + 0], wp[(k + 0) * stride], acc);
            acc = fmaf(xrow[k + 1], wp[(k + 1) * stride], acc);
            acc = fmaf(xrow[k + 2], wp[(k + 2) * stride], acc);
            acc = fmaf(xrow[k + 3], wp[(k + 3) * stride], acc);
        }
        outs[wave][lane] = acc;
    }
    __syncthreads();

    if (lane < 9) {
        int a = lane;
        decode_emit(pix * 9 + a, outs[wave][a],
                    outs[wave][9 + 4 * a + 0], outs[wave][9 + 4 * a + 1],
                    outs[wave][9 + 4 * a + 2], outs[wave][9 + 4 * a + 3],
                    boxes, keys, cnt, hist);
    }
}

// ---------------- scan: 16 elems/thread serial + one block scan ----------------
__global__ __launch_bounds__(256) void scan_kernel(
    const int* __restrict__ hist, int* __restrict__ base)
{
    __shared__ int tot[256];
    int t = threadIdx.x;
    int v[16];
    int s = 0;
    #pragma unroll
    for (int i = 0; i < 16; ++i) { v[i] = hist[t * 16 + i]; s += v[i]; }
    tot[t] = s;
    __syncthreads();
    for (int d = 1; d < 256; d <<= 1) {
        int x = (t >= d) ? tot[t - d] : 0;
        __syncthreads();
        tot[t] += x;
        __syncthreads();
    }
    int excl = (t == 0) ? 0 : tot[t - 1];
    #pragma unroll
    for (int i = 0; i < 16; ++i) { base[t * 16 + i] = excl; excl += v[i]; }
    if (t == 255) { base[4096] = excl; base[4097] = excl + hist[4096]; }
}

__global__ __launch_bounds__(256) void scatter_kernel(
    const unsigned long long* __restrict__ keys, const int* __restrict__ cnt,
    const int* __restrict__ base, int* __restrict__ cur,
    unsigned long long* __restrict__ skeys)
{
    int i = blockIdx.x * 256 + threadIdx.x;
    if (i < *cnt) {
        unsigned long long k = keys[i];
        int b = (int)(k >> 29);
        int p = base[b] + atomicAdd(&cur[b], 1);
        skeys[p] = k;
    }
}

// ---------------- per-bucket rank sort + top-T gather ----------------
__global__ __launch_bounds__(256) void sortb_kernel(
    const unsigned long long* __restrict__ skeys, const int* __restrict__ base,
    const float4* __restrict__ boxes,
    unsigned long long* __restrict__ sk2,
    float4* __restrict__ cboxes, float* __restrict__ careas)
{
    __shared__ unsigned long long sk[2048];
    int b = blockIdx.x;
    int s0 = base[b];
    int n = base[b + 1] - s0;
    if (n <= 0) return;
    int t = threadIdx.x;
    if (n <= 2048) {
        for (int i = t; i < n; i += 256) sk[i] = skeys[s0 + i];
        __syncthreads();
        for (int i = t; i < n; i += 256) {
            unsigned long long k = sk[i];
            int r = 0;
            for (int j = 0; j < n; ++j) r += (sk[j] < k) ? 1 : 0;
            int pos = s0 + r;
            sk2[pos] = k;
            if (pos < T_TOP) {
                float4 bb = boxes[k & 0x3FFFFull];
                cboxes[pos] = bb;
                careas[pos] = (bb.z - bb.x) * (bb.w - bb.y);
            }
        }
    } else {
        const unsigned long long* src = skeys + s0;
        for (int i = t; i < n; i += 256) {
            unsigned long long k = src[i];
            int r = 0;
            for (int j = 0; j < n; ++j) r += (src[j] < k) ? 1 : 0;
            int pos = s0 + r;
            sk2[pos] = k;
            if (pos < T_TOP) {
                float4 bb = boxes[k & 0x3FFFFull];
                cboxes[pos] = bb;
                careas[pos] = (bb.z - bb.x) * (bb.w - bb.y);
            }
        }
    }
}

// ---------------- pairwise suppression bitmask (T=4096) ----------------
__global__ __launch_bounds__(256) void mask_kernel(
    const float4* __restrict__ cboxes, const float* __restrict__ careas,
    unsigned long long* __restrict__ msk)
{
    int bi = blockIdx.y, bj = blockIdx.x;
    if (bj < bi) return;
    __shared__ float4 jb[256];
    __shared__ float  ja[256];
    int t = threadIdx.x;
    int j0 = bj << 8;
    jb[t] = cboxes[j0 + t];
    ja[t] = careas[j0 + t];
    __syncthreads();
    int i = (bi << 8) + t;
    float4 ci = cboxes[i];
    float ca = careas[i];
    unsigned long long word = 0;
    for (int jj = 0; jj < 256; ++jj) {
        int j = j0 + jj;
        float4 b = jb[jj];
        float iy = fmaxf(0.f, fminf(ci.z, b.z) - fmaxf(ci.x, b.x));
        float ix = fmaxf(0.f, fminf(ci.w, b.w) - fmaxf(ci.y, b.y));
        float inter = iy * ix;
        float iou = inter / (ca + ja[jj] - inter + 1e-9f);
        bool bit = (j == i) || (j > i && iou > 0.7f);
        if (bit) word |= 1ull << (jj & 63);
        if ((jj & 63) == 63) {
            msk[(size_t)i * TW + (bj << 2) + (jj >> 6)] = word;
            word = 0;
        }
    }
}

// ---------------- greedy walk: LDS-resident fast path + exact fallbacks ----------------
__global__ __launch_bounds__(256) void walk_kernel(
    const unsigned long long* __restrict__ sk2, const int* __restrict__ cnt,
    const float4* __restrict__ cboxes, const float* __restrict__ careas,
    const unsigned long long* __restrict__ msk, const float4* __restrict__ boxes,
    float* __restrict__ out)
{
    __shared__ unsigned long long mlds[FAST_N * 16];   // 128 KB
    __shared__ unsigned long long sup[TW];
    __shared__ float4 sbox[NSEL];
    __shared__ float  sarea[NSEL];
    __shared__ unsigned short sellist[NSEL];
    int tid = threadIdx.x;
    for (int i = tid; i < 1800; i += 256) out[i] = 0.f;
    int total = *cnt;
    int Tc = min(total, T_TOP);
    int FN = min(Tc, FAST_N);
    for (int i = tid; i < FN * 16; i += 256) {
        mlds[i] = msk[(size_t)(i >> 4) * TW + (i & 15)];
    }
    if (tid < TW) sup[tid] = 0ull;
    __syncthreads();
    if (tid >= 64) return;
    int lane = tid;
    int sel = 0;

    // ---- fast path: candidates [0, FN), all state in LDS ----
    {
        int p = 0;
        while (sel < NSEL) {
            int w0 = p >> 6;
            unsigned long long m = 0;
            if (lane < 16 && lane >= w0) {
                m = ~sup[lane];
                if (lane == w0) m &= (~0ull << (p & 63));
            }
            unsigned long long bal = __ballot(m != 0ull);
            if (bal == 0ull) break;
            int w = __builtin_ctzll(bal);
            int bit = __shfl(m ? __builtin_ctzll(m) : 0, w);
            int c = (w << 6) + bit;
            if (c >= FN) break;
            float4 cb = cboxes[c];
            float ca = careas[c];
            if (lane == 0) {
                unsigned long long key = sk2[c];
                out[sel * 4 + 0] = cb.x; out[sel * 4 + 1] = cb.y;
                out[sel * 4 + 2] = cb.z; out[sel * 4 + 3] = cb.w;
                out[1200 + sel] = __uint_as_float(0x3F800000u - (unsigned)(key >> 18));
                out[1500 + sel] = 1.f;
                sbox[sel] = cb;
                sarea[sel] = ca;
                sellist[sel] = (unsigned short)c;
            }
            sel++;
            if (lane < 16) sup[lane] |= mlds[c * 16 + lane];
            p = c + 1;
        }
    }

    // ---- slow path: candidates [FN, Tc) via global mask rows ----
    if (sel < NSEL && Tc > FN) {
        // lazily materialize tail sup words from already-selected rows
        unsigned long long acc = 0ull;
        if (lane >= 16) {
            for (int s = 0; s < sel; ++s)
                acc |= msk[(size_t)sellist[s] * TW + lane];
            sup[lane] = acc;
        }

        auto scanFrom = [&](int p) -> int {
            if (p < 0 || p >= Tc) return -1;
            int w = p >> 6;
            unsigned long long f = (~sup[w]) & (~0ull << (p & 63));
            while (f == 0ull) {
                ++w;
                if (w >= TW) return -1;
                f = ~sup[w];
            }
            int c = (w << 6) + __builtin_ctzll(f);
            return (c < Tc) ? c : -1;
        };

        unsigned long long r0 = 0, r1 = 0, r2n = 0;
        int idx = scanFrom(FN);
        if (idx >= 0) r0 = msk[(size_t)idx * TW + lane];
        int idx2 = (idx >= 0) ? scanFrom(idx + 1) : -1;
        if (idx2 >= 0) r1 = msk[(size_t)idx2 * TW + lane];

        while (idx >= 0 && sel < NSEL) {
            float4 cb = cboxes[idx];
            float ca = careas[idx];
            if (lane == 0) {
                unsigned long long key = sk2[idx];
                out[sel * 4 + 0] = cb.x; out[sel * 4 + 1] = cb.y;
                out[sel * 4 + 2] = cb.z; out[sel * 4 + 3] = cb.w;
                out[1200 + sel] = __uint_as_float(0x3F800000u - (unsigned)(key >> 18));
                out[1500 + sel] = 1.f;
                sbox[sel] = cb;
                sarea[sel] = ca;
            }
            sel++;
            if (sel >= NSEL) break;

            int idx3 = (idx2 >= 0) ? scanFrom(idx2 + 1) : -1;
            if (idx3 >= 0) r2n = msk[(size_t)idx3 * TW + lane];

            sup[lane] |= r0;

            if (idx2 >= 0) {
                unsigned long long w = sup[idx2 >> 6];
                if ((w >> (idx2 & 63)) & 1ull) {
                    idx2 = scanFrom(idx2);
                    if (idx2 >= 0) r1 = msk[(size_t)idx2 * TW + lane];
                    idx3 = (idx2 >= 0) ? scanFrom(idx2 + 1) : -1;
                    if (idx3 >= 0) r2n = msk[(size_t)idx3 * TW + lane];
                }
            }
            idx = idx2; r0 = r1;
            idx2 = idx3; r1 = r2n;
        }
    }

    // ---- exact tail beyond T_TOP ----
    if (sel < NSEL && total > T_TOP) {
        for (int i = T_TOP; i < total && sel < NSEL; ++i) {
            unsigned long long key = sk2[i];
            float4 cb = boxes[key & 0x3FFFFull];
            float ca = (cb.z - cb.x) * (cb.w - cb.y);
            int supp = 0;
            for (int t = lane; t < sel; t += 64) {
                float4 s4 = sbox[t];
                float iy = fmaxf(0.f, fminf(s4.z, cb.z) - fmaxf(s4.x, cb.x));
                float ix = fmaxf(0.f, fminf(s4.w, cb.w) - fmaxf(s4.y, cb.y));
                float inter = iy * ix;
                float iou = inter / (sarea[t] + ca - inter + 1e-9f);
                if (iou > 0.7f) supp = 1;
            }
            if (__ballot(supp) == 0ull) {
                if (lane == 0) {
                    out[sel * 4 + 0] = cb.x; out[sel * 4 + 1] = cb.y;
                    out[sel * 4 + 2] = cb.z; out[sel * 4 + 3] = cb.w;
                    out[1200 + sel] = __uint_as_float(0x3F800000u - (unsigned)(key >> 18));
                    out[1500 + sel] = 1.f;
                    sbox[sel] = cb;
                    sarea[sel] = ca;
                }
                sel++;
            }
        }
    }
}

extern "C" void kernel_launch(void* const* d_in, const int* in_sizes, int n_in,
                              void* d_out, int out_size, void* d_ws, size_t ws_size,
                              hipStream_t stream) {
    const float* feat = (const float*)d_in[0];
    const float* w1   = (const float*)d_in[1];
    const float* b1   = (const float*)d_in[2];
    const float* w2   = (const float*)d_in[3];
    const float* b2   = (const float*)d_in[4];
    const float* w_s  = (const float*)d_in[5];
    const float* b_s  = (const float*)d_in[6];
    const float* w_b  = (const float*)d_in[7];
    const float* b_b  = (const float*)d_in[8];
    float* out = (float*)d_out;
    char* ws = (char*)d_ws;

    if (ws_size >= NWS_TOTAL) {
        _Float16* a1h = (_Float16*)(ws + NWS_A1H);
        _Float16* a1l = (_Float16*)(ws + NWS_A1L);
        _Float16* w1h = (_Float16*)(ws + NWS_W1H);
        _Float16* w1l = (_Float16*)(ws + NWS_W1L);
        _Float16* a2h = (_Float16*)(ws + NWS_A2H);
        _Float16* a2l = (_Float16*)(ws + NWS_A2L);
        _Float16* w2h = (_Float16*)(ws + NWS_W2H);
        _Float16* w2l = (_Float16*)(ws + NWS_W2L);
        _Float16* xh  = (_Float16*)(ws + NWS_X2);
        _Float16* xl  = (_Float16*)(ws + NWS_X2 + 16777216);
        float4* boxes = (float4*)(ws + NWS_BOXES);
        unsigned long long* keys  = (unsigned long long*)(ws + NWS_KEYS);
        unsigned long long* skeys = (unsigned long long*)(ws + NWS_SKEYS);
        int* hist = (int*)(ws + NWS_HIST);
        int* cur  = (int*)(ws + NWS_CUR);
        int* cnt  = (int*)(ws + NWS_CNT);
        int* base = (int*)(ws + NWS_BASE);
        _Float16* wbh = (_Float16*)(ws + NWS_SKEYS);           // dead before scatter writes skeys
        _Float16* wbl = (_Float16*)(ws + NWS_SKEYS + 65536);
        unsigned long long* msk = (unsigned long long*)(ws + NWS_A1H);   // 2 MB
        float4* cbox  = (float4*)(ws + NWS_A1L);
        float*  carea = (float*)(ws + NWS_A1L + 262144);
        unsigned long long* sk2 = keys;

        fused_prep_kernel<<<8269, 256, 0, stream>>>(
            feat, a1h, a1l, w1, w1h, w1l, w2, w2h, w2l,
            w_s, w_b, wbh, wbl, a2h, a2l, (int4*)(ws + NWS_HIST));
        conv_mfma_kernel<1024, true ><<<512, 512, 0, stream>>>(a1h, a1l, w1h, w1l, b1, a2h, a2l);
        conv_mfma_kernel< 512, false><<<512, 512, 0, stream>>>(a2h, a2l, w2h, w2l, b2, xh, xl);
        heads_mfma_kernel<<<128, 256, 0, stream>>>(xh, xl, wbh, wbl, b_s, b_b, boxes, keys, cnt, hist);
        scan_kernel<<<1, 256, 0, stream>>>(hist, base);
        scatter_kernel<<<576, 256, 0, stream>>>(keys, cnt, base, cur, skeys);
        sortb_kernel<<<NB, 256, 0, stream>>>(skeys, base, boxes, sk2, cbox, carea);
        mask_kernel<<<dim3(16, 16), 256, 0, stream>>>(cbox, carea, msk);
        walk_kernel<<<1, 256, 0, stream>>>(sk2, cnt, cbox, carea, msk, boxes, out);
    } else {
        float* x1 = (float*)(ws + WS_X1);
        float* x2 = (float*)(ws + WS_X2);
        float4* boxes = (float4*)(ws + WS_BOXES);
        unsigned long long* keys  = (unsigned long long*)(ws + WS_KEYS);
        unsigned long long* skeys = (unsigned long long*)(ws + WS_SKEYS);
        int* hist = (int*)(ws + WS_HIST);
        int* cur  = (int*)(ws + WS_CUR);
        int* cnt  = (int*)(ws + WS_CNT);
        int* base = (int*)(ws + WS_BASE);
        unsigned long long* msk = (unsigned long long*)(ws + WS_X1);
        float4* cbox  = (float4*)(ws + WS_X2);
        float*  carea = (float*)(ws + WS_X2 + 262144);
        unsigned long long* sk2 = keys;

        hipMemsetAsync(ws + WS_HIST, 0, (WS_CNT - WS_HIST) + 256, stream);
        conv3x3_kernel<1024, true,  true ><<<2048, 256, 0, stream>>>(feat, w1, b1, x1);
        conv3x3_kernel< 512, false, false><<<2048, 256, 0, stream>>>(x1,   w2, b2, x2);
        heads_decode_kernel<<<4096, 256, 0, stream>>>(x2, w_s, b_s, w_b, b_b, boxes, keys, cnt, hist);
        scan_kernel<<<1, 256, 0, stream>>>(hist, base);
        scatter_kernel<<<576, 256, 0, stream>>>(keys, cnt, base, cur, skeys);
        sortb_kernel<<<NB, 256, 0, stream>>>(skeys, base, boxes, sk2, cbox, carea);
        mask_kernel<<<dim3(16, 16), 256, 0, stream>>>(cbox, carea, msk);
        walk_kernel<<<1, 256, 0, stream>>>(sk2, cnt, cbox, carea, msk, boxes, out);
    }
}

// Round 9
// 859.961 us; speedup vs baseline: 1.0383x; 1.0383x over previous
//
#include <hip/hip_runtime.h>

#define HW 128
#define COUTC 512
#define NB 4097
#define NSEL 300
#define T_TOP 4096
#define TW 64           // words per mask row = T_TOP/64
#define FAST_N 1024     // chunk size for the walk

typedef _Float16 half8 __attribute__((ext_vector_type(8)));
typedef _Float16 half4v __attribute__((ext_vector_type(4)));
typedef float floatx4 __attribute__((ext_vector_type(4)));

// ================= fast-path ws layout (bytes) =================
#define NWS_A1H   ((size_t)0)            // 34,611,200  (dead after conv1 -> MSK 2MB)
#define NWS_A1L   ((size_t)34611200)     // (dead after conv1 -> CBOX/CAREA)
#define NWS_W1H   ((size_t)69222400)
#define NWS_W1L   ((size_t)78659584)
#define NWS_A2H   ((size_t)88096768)
#define NWS_A2L   ((size_t)105402368)
#define NWS_W2H   ((size_t)122707968)
#define NWS_W2L   ((size_t)127426560)
#define NWS_X2    ((size_t)132145152)    // xh (16,777,216) + xl (16,777,216)
#define NWS_BOXES ((size_t)165699584)
#define NWS_KEYS  ((size_t)168058880)    // reused as sorted keys (sk2)
#define NWS_SKEYS ((size_t)169238528)    // wbh/wbl live here until heads done
#define NWS_HIST  ((size_t)170418176)
#define NWS_CUR   ((size_t)170434816)
#define NWS_CNT   ((size_t)170451456)
#define NWS_BASE  ((size_t)170451712)
#define NWS_TOTAL ((size_t)170468352)

// ================= fallback ws layout =================
#define WS_X1     ((size_t)0)
#define WS_X2     ((size_t)33554432)
#define WS_BOXES  ((size_t)67108864)
#define WS_KEYS   ((size_t)69468160)
#define WS_SKEYS  ((size_t)70647808)
#define WS_HIST   ((size_t)71827456)
#define WS_CUR    ((size_t)71844096)
#define WS_CNT    ((size_t)71860736)
#define WS_BASE   ((size_t)71860992)

__device__ __forceinline__ void glds16(const void* g, void* l) {
    __builtin_amdgcn_global_load_lds(
        (const __attribute__((address_space(1))) void*)g,
        (__attribute__((address_space(3))) void*)l, 16, 0, 0);
}

// Activation layout (per padded row pr): [chunk(CIN/32)][sub(4)][pc(130)][8ch]
// Weight layout (per tap): [chunk(CIN/32)][sub(4)][oc(512)][8ch]
// conv2-output (heads input) layout (per row h): [chunk(16)][sub(4)][pix(128)][8ch], rowstride 65536 halves

// ---------------- weight convert body ----------------
template<int CIN>
__device__ __forceinline__ void convert_w_body(
    int b, const float* __restrict__ w, _Float16* __restrict__ wh, _Float16* __restrict__ wl)
{
    constexpr int NU = CIN / 8;
    int gid = b * 256 + threadIdx.x;
    int oc = gid & 511;
    int rest = gid >> 9;
    int u = rest & (NU - 1);
    int tap = rest / NU;
    if (tap >= 9) return;
    int k0 = u * 8;
    half8 vh, vl;
    #pragma unroll
    for (int j = 0; j < 8; ++j) {
        float v = w[((size_t)tap * CIN + k0 + j) * 512 + oc] * 64.f;
        _Float16 hi = (_Float16)v;
        vh[j] = hi;
        vl[j] = (_Float16)(v - (float)hi);
    }
    size_t o = (size_t)tap * CIN * 512 + (size_t)(k0 >> 5) * 16384
             + (size_t)((k0 >> 3) & 3) * 4096 + (size_t)oc * 8;
    *(half8*)(wh + o) = vh;
    *(half8*)(wl + o) = vl;
}

// ---------------- fused front-end: feature convert + all weight prep + hist/cur/cnt zero -----
__global__ __launch_bounds__(256) void fused_prep_kernel(
    const float* __restrict__ feat, _Float16* __restrict__ ah, _Float16* __restrict__ al,
    const float* __restrict__ w1, _Float16* __restrict__ w1h, _Float16* __restrict__ w1l,
    const float* __restrict__ w2, _Float16* __restrict__ w2h, _Float16* __restrict__ w2l,
    const float* __restrict__ w_s, const float* __restrict__ w_b,
    _Float16* __restrict__ wbh, _Float16* __restrict__ wbl,
    _Float16* __restrict__ a2h, _Float16* __restrict__ a2l,
    int4* __restrict__ zeros)
{
    __shared__ __align__(16) _Float16 lh[130 * 32];
    __shared__ __align__(16) _Float16 ll[130 * 32];
    int b = blockIdx.x;
    if (b < 4160) {      // ---- feature convert: LDS transpose, coalesced both ways ----
        int pr = b % 130;        // 0..129
        int chunk = b / 130;     // 0..31
        int t = threadIdx.x;
        int c  = t & 31;
        int pg = t >> 5;         // 0..7
        bool interior = (pr >= 1 && pr <= 128);
        if (interior) {
            for (int px = pg; px < 128; px += 8) {
                float x = feat[((size_t)(pr - 1) * 128 + px) * 1024 + chunk * 32 + c];
                x = fmaxf(x, 0.f);
                _Float16 hi = (_Float16)x;
                lh[(px + 1) * 32 + c] = hi;
                ll[(px + 1) * 32 + c] = (_Float16)(x - (float)hi);
            }
        } else {
            for (int px = pg; px < 128; px += 8) {
                lh[(px + 1) * 32 + c] = (_Float16)0.f;
                ll[(px + 1) * 32 + c] = (_Float16)0.f;
            }
        }
        if (t < 32) {
            lh[t] = (_Float16)0.f;          ll[t] = (_Float16)0.f;
            lh[129 * 32 + t] = (_Float16)0.f; ll[129 * 32 + t] = (_Float16)0.f;
        }
        __syncthreads();
        size_t base = (size_t)pr * 133120 + (size_t)chunk * 4160;
        for (int i = t; i < 520; i += 256) {
            int sub = i / 130;
            int pc  = i - sub * 130;
            *(float4*)&ah[base + sub * 1040 + pc * 8] = *(const float4*)&lh[pc * 32 + sub * 8];
            *(float4*)&al[base + sub * 1040 + pc * 8] = *(const float4*)&ll[pc * 32 + sub * 8];
        }
        return;
    }
    b -= 4160;
    if (b < 2304) { convert_w_body<1024>(b, w1, w1h, w1l); return; }
    if (b < 3456) { convert_w_body<512>(b - 2304, w2, w2h, w2l); return; }
    if (b < 3584) {      // ---- head weights: 32768 = 64n x 512k ----
        int gid = (b - 3456) * 256 + threadIdx.x;
        int n = gid & 63;
        int k = gid >> 6;
        float v = 0.f;
        if (n < 9)       v = w_s[k * 9 + n] * 64.f;
        else if (n < 45) v = w_b[k * 36 + (n - 9)] * 64.f;
        _Float16 hi = (_Float16)v;
        size_t o = (size_t)(k >> 5) * 2048 + (size_t)((k >> 3) & 3) * 512 + (size_t)n * 8 + (k & 7);
        wbh[o] = hi;
        wbl[o] = (_Float16)(v - (float)hi);
        return;
    }
    if (b < 4100) {      // ---- a2 pad ring (516 blocks) ----
        int i = b - 3584;
        int pr, pc;
        if (i < 130)      { pr = 0;        pc = i; }
        else if (i < 260) { pr = 129;      pc = i - 130; }
        else if (i < 388) { pr = i - 259;  pc = 0; }
        else              { pr = i - 387;  pc = 129; }
        int t = threadIdx.x;
        if (t >= 128) return;
        _Float16* dst = (t & 64) ? a2l : a2h;
        int u = t & 63;
        size_t o = (size_t)pr * 66560 + (size_t)(u >> 2) * 4160 + (size_t)(u & 3) * 1040 + (size_t)pc * 8;
        *(float4*)(dst + o) = make_float4(0.f, 0.f, 0.f, 0.f);
        return;
    }
    {                    // ---- hist/cur/cnt zero: 33536 B = 2096 int4 (9 blocks) ----
        int gid = (b - 4100) * 256 + threadIdx.x;
        if (gid < 2096) zeros[gid] = make_int4(0, 0, 0, 0);
    }
}

// ---------------- conv 3x3 fp16-split MFMA, 128x128 tile, BK=64, 512-thread blocks ----------------
// Round-7 proven optimum (conv1 337us, FETCH 373MB, MfmaUtil 70%). Rounds 1/5/6: any pipelining
// or block-remap that breaks the lockstep __syncthreads choreography inflates FETCH 1.6-3x and
// regresses. Round 8: B-direct-to-register also regresses (wm-duplicated B loads, 12 vs 8
// VMEM/step). This structure is the conv plateau -- do not touch staging or barriers.
// Per-accumulator FP sequence (tap -> kc32 -> hh,hl,lh) IDENTICAL: bit-exact outputs.
template<int CIN, bool PAD>
__global__ __launch_bounds__(512, 4) void conv_mfma_kernel(
    const _Float16* __restrict__ ah, const _Float16* __restrict__ al,
    const _Float16* __restrict__ wh, const _Float16* __restrict__ wl,
    const float* __restrict__ bias,
    _Float16* __restrict__ oh, _Float16* __restrict__ ol)
{
    constexpr int ROWSTR = CIN * 130;
    constexpr int TAPW   = CIN * 512;
    __shared__ __align__(16) _Float16 lds[32768];

    int bx = blockIdx.x;          // grid 512: bx%8 == h%8 (baseline XCD choreography)
    int h  = bx & 127;
    int n0 = (bx >> 7) << 7;

    int tid  = threadIdx.x;
    int wave = tid >> 6;          // 0..7
    int lane = tid & 63;
    int fr = lane & 15;
    int fq = lane >> 4;

    int aoff0 = fq * 1040 + (16 * wave + fr) * 8;
    int boff0 = fq * 4096 + (n0 + 16 * wave + fr) * 8;

    int wm = wave & 1, wn = wave >> 1;   // wn 0..3

    floatx4 acc[4][2];
    #pragma unroll
    for (int i = 0; i < 4; ++i)
        #pragma unroll
        for (int j = 0; j < 2; ++j)
            acc[i][j] = (floatx4){0.f, 0.f, 0.f, 0.f};

    #pragma unroll
    for (int tap = 0; tap < 9; ++tap) {
        int dy = tap / 3 - 1, dx = tap % 3 - 1;
        const _Float16* gAh = ah + (size_t)(h + dy + 1) * ROWSTR + (dx + 1) * 8;
        const _Float16* gAl = al + (size_t)(h + dy + 1) * ROWSTR + (dx + 1) * 8;
        const _Float16* gBh = wh + (size_t)tap * TAPW;
        const _Float16* gBl = wl + (size_t)tap * TAPW;

        for (int kc = 0; kc < CIN; kc += 64) {
            #pragma unroll
            for (int s = 0; s < 2; ++s) {
                int ab = ((kc >> 5) + s) * 4160;
                int bb = ((kc >> 5) + s) * 16384;
                _Float16* dA = lds +          s * 4096 + wave * 512;
                _Float16* dL = lds + 8192  +  s * 4096 + wave * 512;
                _Float16* dB = lds + 16384 +  s * 4096 + wave * 512;
                _Float16* dC = lds + 24576 +  s * 4096 + wave * 512;
                glds16(gAh + ab + aoff0, dA);
                glds16(gAl + ab + aoff0, dL);
                glds16(gBh + bb + boff0, dB);
                glds16(gBl + bb + boff0, dC);
            }
            __syncthreads();

            #pragma unroll
            for (int s = 0; s < 2; ++s) {
                const _Float16* rAh = lds +          s * 4096 + wm * 2048 + fq * 128 + fr * 8;
                const _Float16* rAl = rAh + 8192;
                const _Float16* rBh = lds + 16384 +  s * 4096 + wn * 1024 + fq * 128 + fr * 8;
                const _Float16* rBl = rBh + 8192;

                half8 fah[4], fal[4], fbh[2], fbl[2];
                #pragma unroll
                for (int i = 0; i < 4; ++i) {
                    fah[i] = *(const half8*)(rAh + i * 512);
                    fal[i] = *(const half8*)(rAl + i * 512);
                }
                #pragma unroll
                for (int j = 0; j < 2; ++j) {
                    fbh[j] = *(const half8*)(rBh + j * 512);
                    fbl[j] = *(const half8*)(rBl + j * 512);
                }
                #pragma unroll
                for (int i = 0; i < 4; ++i)
                    #pragma unroll
                    for (int j = 0; j < 2; ++j)
                        acc[i][j] = __builtin_amdgcn_mfma_f32_16x16x32_f16(fah[i], fbh[j], acc[i][j], 0, 0, 0);
                #pragma unroll
                for (int i = 0; i < 4; ++i)
                    #pragma unroll
                    for (int j = 0; j < 2; ++j)
                        acc[i][j] = __builtin_amdgcn_mfma_f32_16x16x32_f16(fah[i], fbl[j], acc[i][j], 0, 0, 0);
                #pragma unroll
                for (int i = 0; i < 4; ++i)
                    #pragma unroll
                    for (int j = 0; j < 2; ++j)
                        acc[i][j] = __builtin_amdgcn_mfma_f32_16x16x32_f16(fal[i], fbh[j], acc[i][j], 0, 0, 0);
            }
            __syncthreads();
        }
    }

    const float scale = 1.f / 64.f;
    int em = 64 * wm + fq * 4;
    int en = 32 * wn + fr;
    #pragma unroll
    for (int j = 0; j < 2; ++j) {
        int oc = n0 + en + 16 * j;
        float b2 = bias[oc];
        #pragma unroll
        for (int i = 0; i < 4; ++i) {
            #pragma unroll
            for (int r = 0; r < 4; ++r) {
                int w = em + 16 * i + r;
                float v = fmaf(acc[i][j][r], scale, b2);
                if (PAD) {
                    v = fmaxf(v, 0.f);
                    _Float16 hi = (_Float16)v;
                    size_t o = (size_t)(h + 1) * 66560 + (size_t)(oc >> 5) * 4160
                             + (size_t)((oc >> 3) & 3) * 1040 + (size_t)(w + 1) * 8 + (oc & 7);
                    oh[o] = hi;
                    ol[o] = (_Float16)(v - (float)hi);
                } else {
                    _Float16 hi = (_Float16)v;
                    size_t o = (size_t)h * 65536 + (size_t)(oc >> 5) * 4096
                             + (size_t)((oc >> 3) & 3) * 1024 + (size_t)w * 8 + (oc & 7);
                    oh[o] = hi;
                    ol[o] = (_Float16)(v - (float)hi);
                }
            }
        }
    }
}

// ---------------- decode helper ----------------
__device__ __forceinline__ void decode_emit(
    int gi, float z, float dyv, float dxv, float dhv, float dwv,
    float4* __restrict__ boxes, unsigned long long* __restrict__ keys,
    int* __restrict__ cnt, int* __restrict__ hist)
{
    int a = gi % 9;
    int pix = gi / 9;
    int h = pix >> 7, w = pix & 127;
    float sc  = (a < 3) ? 128.f : ((a < 6) ? 256.f : 512.f);
    int r = a - (a / 3) * 3;
    float ratio = (r == 0) ? 0.5f : ((r == 1) ? 1.f : 2.f);
    float sr = sqrtf(ratio);
    float ahh = sc * sr, aww = sc / sr;
    float acy = ((float)h + 0.5f) * 16.f;
    float acx = ((float)w + 0.5f) * 16.f;
    float cy = fmaf(dyv, ahh, acy);
    float cx = fmaf(dxv, aww, acx);
    float hh = ahh * expf(dhv);
    float ww = aww * expf(dwv);
    float y1 = fminf(fmaxf(cy - 0.5f * hh, 0.f), 2048.f);
    float x1 = fminf(fmaxf(cx - 0.5f * ww, 0.f), 2048.f);
    float y2 = fminf(fmaxf(cy + 0.5f * hh, 0.f), 2048.f);
    float x2 = fminf(fmaxf(cx + 0.5f * ww, 0.f), 2048.f);
    boxes[gi] = make_float4(y1, x1, y2, x2);
    float s = 1.f / (1.f + expf(-z));
    if (s >= 0.5f) {
        unsigned u = __float_as_uint(s);
        unsigned d = 0x3F800000u - u;
        unsigned long long key = ((unsigned long long)d << 18) | (unsigned)gi;
        int p = atomicAdd(cnt, 1);
        keys[p] = key;
        atomicAdd(&hist[d >> 11], 1);
    }
}

// ---------------- heads via MFMA: 128 blocks, M=128 px, N=48(pad 64), K=512 ----------------
__global__ __launch_bounds__(256) void heads_mfma_kernel(
    const _Float16* __restrict__ xh, const _Float16* __restrict__ xl,
    const _Float16* __restrict__ wbh, const _Float16* __restrict__ wbl,
    const float* __restrict__ b_s, const float* __restrict__ b_b,
    float4* __restrict__ boxes, unsigned long long* __restrict__ keys,
    int* __restrict__ cnt, int* __restrict__ hist)
{
    __shared__ __align__(16) char smem[24576];
    _Float16* sAh = (_Float16*)smem;             // 4096 halves: [sub4][pix128][8]
    _Float16* sAl = (_Float16*)(smem + 8192);
    _Float16* sBh = (_Float16*)(smem + 16384);   // 2048 halves: [sub4][n64][8]
    _Float16* sBl = (_Float16*)(smem + 20480);
    float* outs = (float*)smem;                  // overlay after K-loop: [128][48] = 24576 B
    __shared__ float sb[48];

    int tid  = threadIdx.x;
    int wave = tid >> 6;
    int lane = tid & 63;
    int fr = lane & 15;
    int fq = lane >> 4;
    if (tid < 48) sb[tid] = (tid < 9) ? b_s[tid] : ((tid < 45) ? b_b[tid - 9] : 0.f);

    int h = blockIdx.x;
    int wm = wave & 1, wn = wave >> 1;

    floatx4 acc[4][2];
    #pragma unroll
    for (int i = 0; i < 4; ++i)
        #pragma unroll
        for (int j = 0; j < 2; ++j)
            acc[i][j] = (floatx4){0.f, 0.f, 0.f, 0.f};

    for (int kc = 0; kc < 16; ++kc) {
        const _Float16* gxh = xh + (size_t)h * 65536 + kc * 4096;
        const _Float16* gxl = xl + (size_t)h * 65536 + kc * 4096;
        glds16(gxh + tid * 8,        sAh + tid * 8);
        glds16(gxh + 2048 + tid * 8, sAh + 2048 + tid * 8);
        glds16(gxl + tid * 8,        sAl + tid * 8);
        glds16(gxl + 2048 + tid * 8, sAl + 2048 + tid * 8);
        glds16(wbh + kc * 2048 + tid * 8, sBh + tid * 8);
        glds16(wbl + kc * 2048 + tid * 8, sBl + tid * 8);
        __syncthreads();

        half8 fah[4], fal[4], fbh[2], fbl[2];
        #pragma unroll
        for (int i = 0; i < 4; ++i) {
            int px = wm * 64 + 16 * i + fr;
            int aaddr = fq * 1024 + px * 8;
            fah[i] = *(const half8*)(sAh + aaddr);
            fal[i] = *(const half8*)(sAl + aaddr);
        }
        #pragma unroll
        for (int j = 0; j < 2; ++j) {
            int n = wn * 32 + 16 * j + fr;
            int baddr = fq * 512 + n * 8;
            fbh[j] = *(const half8*)(sBh + baddr);
            fbl[j] = *(const half8*)(sBl + baddr);
        }
        #pragma unroll
        for (int i = 0; i < 4; ++i)
            #pragma unroll
            for (int j = 0; j < 2; ++j) {
                acc[i][j] = __builtin_amdgcn_mfma_f32_16x16x32_f16(fah[i], fbh[j], acc[i][j], 0, 0, 0);
                acc[i][j] = __builtin_amdgcn_mfma_f32_16x16x32_f16(fah[i], fbl[j], acc[i][j], 0, 0, 0);
                acc[i][j] = __builtin_amdgcn_mfma_f32_16x16x32_f16(fal[i], fbh[j], acc[i][j], 0, 0, 0);
            }
        __syncthreads();
    }

    const float scale = 1.f / 64.f;
    #pragma unroll
    for (int i = 0; i < 4; ++i)
        #pragma unroll
        for (int j = 0; j < 2; ++j)
            #pragma unroll
            for (int r = 0; r < 4; ++r) {
                int px = wm * 64 + 16 * i + fq * 4 + r;
                int n = wn * 32 + 16 * j + fr;
                if (n < 48)
                    outs[px * 48 + n] = fmaf(acc[i][j][r], scale, sb[n]);
            }
    __syncthreads();

    if (tid < 128) {
        int p = tid;
        #pragma unroll
        for (int a = 0; a < 9; ++a) {
            float z   = outs[p * 48 + a];
            float dyv = outs[p * 48 + 9 + 4 * a + 0];
            float dxv = outs[p * 48 + 9 + 4 * a + 1];
            float dhv = outs[p * 48 + 9 + 4 * a + 2];
            float dwv = outs[p * 48 + 9 + 4 * a + 3];
            int gi = (h * 128 + p) * 9 + a;
            decode_emit(gi, z, dyv, dxv, dhv, dwv, boxes, keys, cnt, hist);
        }
    }
}

// ---------------- fallback fp32 conv ----------------
template<int CIN, bool RELU_IN, bool RELU_OUT>
__global__ __launch_bounds__(256) void conv3x3_kernel(
    const float* __restrict__ in, const float* __restrict__ wgt,
    const float* __restrict__ bias, float* __restrict__ out)
{
    __shared__ float As[32][68];
    __shared__ float Bs[32][64];
    int bx = blockIdx.x;
    int mtile = bx & 255, ntile = bx >> 8;
    int h = mtile >> 1, w0 = (mtile & 1) << 6, n0 = ntile << 6;
    int tid = threadIdx.x, ty = tid >> 4, tx = tid & 15;
    float acc[4][4] = {{0.f}};
    const int KTOT = 9 * CIN;
    for (int k0 = 0; k0 < KTOT; k0 += 32) {
        int tap = k0 / CIN, icb = k0 % CIN;
        int dy = tap / 3 - 1, dx = tap % 3 - 1;
        int row = h + dy;
        bool rowok = ((unsigned)row < HW);
        {
            int pix = tid >> 3, cs = (tid & 7) << 2;
            #pragma unroll
            for (int p = 0; p < 2; ++p) {
                int px = pix + p * 32;
                int wcol = w0 + px + dx;
                float4 v = make_float4(0.f, 0.f, 0.f, 0.f);
                if (rowok && (unsigned)wcol < HW) {
                    v = *(const float4*)&in[((size_t)row * HW + wcol) * CIN + icb + cs];
                    if (RELU_IN) {
                        v.x = fmaxf(v.x, 0.f); v.y = fmaxf(v.y, 0.f);
                        v.z = fmaxf(v.z, 0.f); v.w = fmaxf(v.w, 0.f);
                    }
                }
                As[cs + 0][px] = v.x; As[cs + 1][px] = v.y;
                As[cs + 2][px] = v.z; As[cs + 3][px] = v.w;
            }
        }
        {
            int kr = tid >> 4, nc = (tid & 15) << 2;
            #pragma unroll
            for (int p = 0; p < 2; ++p) {
                int k = kr + p * 16;
                *(float4*)&Bs[k][nc] = *(const float4*)&wgt[(size_t)(k0 + k) * COUTC + n0 + nc];
            }
        }
        __syncthreads();
        #pragma unroll
        for (int kk = 0; kk < 32; ++kk) {
            float4 a = *(const float4*)&As[kk][ty << 2];
            float4 b = *(const float4*)&Bs[kk][tx << 2];
            float av[4] = {a.x, a.y, a.z, a.w};
            float bv[4] = {b.x, b.y, b.z, b.w};
            #pragma unroll
            for (int i = 0; i < 4; ++i)
                #pragma unroll
                for (int j = 0; j < 4; ++j)
                    acc[i][j] = fmaf(av[i], bv[j], acc[i][j]);
        }
        __syncthreads();
    }
    float4 bi = *(const float4*)&bias[n0 + (tx << 2)];
    float bv2[4] = {bi.x, bi.y, bi.z, bi.w};
    #pragma unroll
    for (int i = 0; i < 4; ++i) {
        float4 o;
        o.x = acc[i][0] + bv2[0]; o.y = acc[i][1] + bv2[1];
        o.z = acc[i][2] + bv2[2]; o.w = acc[i][3] + bv2[3];
        if (RELU_OUT) {
            o.x = fmaxf(o.x, 0.f); o.y = fmaxf(o.y, 0.f);
            o.z = fmaxf(o.z, 0.f); o.w = fmaxf(o.w, 0.f);
        }
        *(float4*)&out[((size_t)(h * HW) + w0 + (ty << 2) + i) * COUTC + n0 + (tx << 2)] = o;
    }
}

// ---------------- fallback heads ----------------
__global__ __launch_bounds__(256) void heads_decode_kernel(
    const float* __restrict__ x, const float* __restrict__ w_s, const float* __restrict__ b_s,
    const float* __restrict__ w_b, const float* __restrict__ b_b,
    float4* __restrict__ boxes, unsigned long long* __restrict__ keys,
    int* __restrict__ cnt, int* __restrict__ hist)
{
    __shared__ float xs[4][512];
    __shared__ float outs[4][45];
    int wave = threadIdx.x >> 6;
    int lane = threadIdx.x & 63;
    int pix  = blockIdx.x * 4 + wave;

    const float4* xp = (const float4*)&x[(size_t)pix * COUTC];
    *(float4*)&xs[wave][lane * 4]       = xp[lane];
    *(float4*)&xs[wave][256 + lane * 4] = xp[64 + lane];
    __syncthreads();

    if (lane < 45) {
        const float* wp; int stride; float acc;
        if (lane < 9) { wp = w_s + lane;       stride = 9;  acc = b_s[lane]; }
        else          { wp = w_b + (lane - 9); stride = 36; acc = b_b[lane - 9]; }
        const float* xrow = xs[wave];
        for (int k = 0; k < 512; k += 4) {
            acc = fmaf(xrow[k + 0], wp[(k + 0) * stride], acc);
            acc = fmaf(xrow[k + 1], wp[(k + 1) * stride], acc);
            acc = fmaf(xrow[k + 2], wp[(k + 2) * stride], acc);
            acc = fmaf(xrow[k + 3], wp[(k + 3) * stride], acc);
        }
        outs[wave][lane] = acc;
    }
    __syncthreads();

    if (lane < 9) {
        int a = lane;
        decode_emit(pix * 9 + a, outs[wave][a],
                    outs[wave][9 + 4 * a + 0], outs[wave][9 + 4 * a + 1],
                    outs[wave][9 + 4 * a + 2], outs[wave][9 + 4 * a + 3],
                    boxes, keys, cnt, hist);
    }
}

// ---------------- scan: 16 elems/thread serial + one block scan ----------------
__global__ __launch_bounds__(256) void scan_kernel(
    const int* __restrict__ hist, int* __restrict__ base)
{
    __shared__ int tot[256];
    int t = threadIdx.x;
    int v[16];
    int s = 0;
    #pragma unroll
    for (int i = 0; i < 16; ++i) { v[i] = hist[t * 16 + i]; s += v[i]; }
    tot[t] = s;
    __syncthreads();
    for (int d = 1; d < 256; d <<= 1) {
        int x = (t >= d) ? tot[t - d] : 0;
        __syncthreads();
        tot[t] += x;
        __syncthreads();
    }
    int excl = (t == 0) ? 0 : tot[t - 1];
    #pragma unroll
    for (int i = 0; i < 16; ++i) { base[t * 16 + i] = excl; excl += v[i]; }
    if (t == 255) { base[4096] = excl; base[4097] = excl + hist[4096]; }
}

__global__ __launch_bounds__(256) void scatter_kernel(
    const unsigned long long* __restrict__ keys, const int* __restrict__ cnt,
    const int* __restrict__ base, int* __restrict__ cur,
    unsigned long long* __restrict__ skeys)
{
    int i = blockIdx.x * 256 + threadIdx.x;
    if (i < *cnt) {
        unsigned long long k = keys[i];
        int b = (int)(k >> 29);
        int p = base[b] + atomicAdd(&cur[b], 1);
        skeys[p] = k;
    }
}

// ---------------- per-bucket rank sort + top-T gather ----------------
__global__ __launch_bounds__(256) void sortb_kernel(
    const unsigned long long* __restrict__ skeys, const int* __restrict__ base,
    const float4* __restrict__ boxes,
    unsigned long long* __restrict__ sk2,
    float4* __restrict__ cboxes, float* __restrict__ careas)
{
    __shared__ unsigned long long sk[2048];
    int b = blockIdx.x;
    int s0 = base[b];
    int n = base[b + 1] - s0;
    if (n <= 0) return;
    int t = threadIdx.x;
    if (n <= 2048) {
        for (int i = t; i < n; i += 256) sk[i] = skeys[s0 + i];
        __syncthreads();
        for (int i = t; i < n; i += 256) {
            unsigned long long k = sk[i];
            int r = 0;
            for (int j = 0; j < n; ++j) r += (sk[j] < k) ? 1 : 0;
            int pos = s0 + r;
            sk2[pos] = k;
            if (pos < T_TOP) {
                float4 bb = boxes[k & 0x3FFFFull];
                cboxes[pos] = bb;
                careas[pos] = (bb.z - bb.x) * (bb.w - bb.y);
            }
        }
    } else {
        const unsigned long long* src = skeys + s0;
        for (int i = t; i < n; i += 256) {
            unsigned long long k = src[i];
            int r = 0;
            for (int j = 0; j < n; ++j) r += (src[j] < k) ? 1 : 0;
            int pos = s0 + r;
            sk2[pos] = k;
            if (pos < T_TOP) {
                float4 bb = boxes[k & 0x3FFFFull];
                cboxes[pos] = bb;
                careas[pos] = (bb.z - bb.x) * (bb.w - bb.y);
            }
        }
    }
}

// ---------------- pairwise suppression bitmask (T=4096) ----------------
__global__ __launch_bounds__(256) void mask_kernel(
    const float4* __restrict__ cboxes, const float* __restrict__ careas,
    unsigned long long* __restrict__ msk)
{
    int bi = blockIdx.y, bj = blockIdx.x;
    if (bj < bi) return;
    __shared__ float4 jb[256];
    __shared__ float  ja[256];
    int t = threadIdx.x;
    int j0 = bj << 8;
    jb[t] = cboxes[j0 + t];
    ja[t] = careas[j0 + t];
    __syncthreads();
    int i = (bi << 8) + t;
    float4 ci = cboxes[i];
    float ca = careas[i];
    unsigned long long word = 0;
    for (int jj = 0; jj < 256; ++jj) {
        int j = j0 + jj;
        float4 b = jb[jj];
        float iy = fmaxf(0.f, fminf(ci.z, b.z) - fmaxf(ci.x, b.x));
        float ix = fmaxf(0.f, fminf(ci.w, b.w) - fmaxf(ci.y, b.y));
        float inter = iy * ix;
        float iou = inter / (ca + ja[jj] - inter + 1e-9f);
        bool bit = (j == i) || (j > i && iou > 0.7f);
        if (bit) word |= 1ull << (jj & 63);
        if ((jj & 63) == 63) {
            msk[(size_t)i * TW + (bj << 2) + (jj >> 6)] = word;
            word = 0;
        }
    }
}

// ---------------- greedy walk: chunked all-LDS scan ----------------
// The old FAST_N=1024 fast path fell back to a latency-serialized slow path: one dependent
// ~L3-latency mask-row fetch per selection past candidate 1024 (speculation fails whenever the
// just-selected row suppresses the speculated next -- common for neighboring anchors). Chunked
// version walks ALL of [0, T_TOP) at LDS speed: per 1024-chunk, (a) 256-thread bulk load of the
// chunk's 1024x16-word diagonal mask block (128KB), (b) one BATCHED OR of not-yet-applied
// selected rows' full mask rows into sup (independent loads -> single round-trip), (c) in-LDS
// greedy scan. Deferred cross-chunk OR is exactly equivalent: intra-chunk suppression is
// immediate via the diagonal block; cross-chunk bits are only consulted after the boundary OR.
// Selection order (ascending sorted index, lowest-unsuppressed-first) is bit-identical.
__global__ __launch_bounds__(256) void walk_kernel(
    const unsigned long long* __restrict__ sk2, const int* __restrict__ cnt,
    const float4* __restrict__ cboxes, const float* __restrict__ careas,
    const unsigned long long* __restrict__ msk, const float4* __restrict__ boxes,
    float* __restrict__ out)
{
    __shared__ unsigned long long mlds[FAST_N * 16];   // 128 KB: chunk diagonal block
    __shared__ unsigned long long sup[TW];
    __shared__ float4 sbox[NSEL];
    __shared__ float  sarea[NSEL];
    __shared__ unsigned short sellist[NSEL];
    __shared__ int s_sel, s_orpos;
    int tid = threadIdx.x;
    for (int i = tid; i < 1800; i += 256) out[i] = 0.f;
    int total = *cnt;
    int Tc = min(total, T_TOP);
    if (tid < TW) sup[tid] = 0ull;
    if (tid == 0) { s_sel = 0; s_orpos = 0; }
    __syncthreads();

    for (int cb = 0; cb < Tc; cb += FAST_N) {
        int clen = min(FAST_N, Tc - cb);
        int wlo = cb >> 6;
        // (a) bulk load chunk diagonal block (rows [cb, cb+clen), words [wlo, wlo+16))
        for (int i = tid; i < clen * 16; i += 256)
            mlds[i] = msk[(size_t)(cb + (i >> 4)) * TW + wlo + (i & 15)];
        __syncthreads();
        if (tid < 64) {
            int lane = tid;
            int sel = s_sel;
            // (b) batched cross-chunk OR of rows selected in earlier chunks
            unsigned long long acc = 0ull;
            for (int s = s_orpos; s < sel; ++s)
                acc |= msk[(size_t)sellist[s] * TW + lane];
            sup[lane] |= acc;
            if (lane == 0) s_orpos = sel;
            // (c) in-LDS greedy scan of this chunk
            int p = cb;
            while (sel < NSEL) {
                int w0 = p >> 6;
                unsigned long long m = 0;
                if (lane < 16 && wlo + lane >= w0) {
                    m = ~sup[wlo + lane];
                    if (wlo + lane == w0) m &= (~0ull << (p & 63));
                }
                unsigned long long bal = __ballot(m != 0ull);
                if (bal == 0ull) break;                 // chunk exhausted
                int w = __builtin_ctzll(bal);
                int bit = __shfl(m ? __builtin_ctzll(m) : 0, w);
                int c = ((wlo + w) << 6) + bit;
                if (c >= cb + clen) break;              // beyond chunk end
                float4 cbx = cboxes[c];
                float ca = careas[c];
                if (lane == 0) {
                    unsigned long long key = sk2[c];
                    out[sel * 4 + 0] = cbx.x; out[sel * 4 + 1] = cbx.y;
                    out[sel * 4 + 2] = cbx.z; out[sel * 4 + 3] = cbx.w;
                    out[1200 + sel] = __uint_as_float(0x3F800000u - (unsigned)(key >> 18));
                    out[1500 + sel] = 1.f;
                    sbox[sel] = cbx;
                    sarea[sel] = ca;
                    sellist[sel] = (unsigned short)c;
                }
                sel++;
                if (lane < 16) sup[wlo + lane] |= mlds[(c - cb) * 16 + lane];
                p = c + 1;
            }
            if (lane == 0) s_sel = sel;
        }
        __syncthreads();
        if (s_sel >= NSEL) break;
    }

    if (tid >= 64) return;
    int lane = tid;
    int sel = s_sel;

    // ---- exact tail beyond T_TOP (unchanged) ----
    if (sel < NSEL && total > T_TOP) {
        for (int i = T_TOP; i < total && sel < NSEL; ++i) {
            unsigned long long key = sk2[i];
            float4 cb = boxes[key & 0x3FFFFull];
            float ca = (cb.z - cb.x) * (cb.w - cb.y);
            int supp = 0;
            for (int t = lane; t < sel; t += 64) {
                float4 s4 = sbox[t];
                float iy = fmaxf(0.f, fminf(s4.z, cb.z) - fmaxf(s4.x, cb.x));
                float ix = fmaxf(0.f, fminf(s4.w, cb.w) - fmaxf(s4.y, cb.y));
                float inter = iy * ix;
                float iou = inter / (sarea[t] + ca - inter + 1e-9f);
                if (iou > 0.7f) supp = 1;
            }
            if (__ballot(supp) == 0ull) {
                if (lane == 0) {
                    out[sel * 4 + 0] = cb.x; out[sel * 4 + 1] = cb.y;
                    out[sel * 4 + 2] = cb.z; out[sel * 4 + 3] = cb.w;
                    out[1200 + sel] = __uint_as_float(0x3F800000u - (unsigned)(key >> 18));
                    out[1500 + sel] = 1.f;
                    sbox[sel] = cb;
                    sarea[sel] = ca;
                }
                sel++;
            }
        }
    }
}

extern "C" void kernel_launch(void* const* d_in, const int* in_sizes, int n_in,
                              void* d_out, int out_size, void* d_ws, size_t ws_size,
                              hipStream_t stream) {
    const float* feat = (const float*)d_in[0];
    const float* w1   = (const float*)d_in[1];
    const float* b1   = (const float*)d_in[2];
    const float* w2   = (const float*)d_in[3];
    const float* b2   = (const float*)d_in[4];
    const float* w_s  = (const float*)d_in[5];
    const float* b_s  = (const float*)d_in[6];
    const float* w_b  = (const float*)d_in[7];
    const float* b_b  = (const float*)d_in[8];
    float* out = (float*)d_out;
    char* ws = (char*)d_ws;

    if (ws_size >= NWS_TOTAL) {
        _Float16* a1h = (_Float16*)(ws + NWS_A1H);
        _Float16* a1l = (_Float16*)(ws + NWS_A1L);
        _Float16* w1h = (_Float16*)(ws + NWS_W1H);
        _Float16* w1l = (_Float16*)(ws + NWS_W1L);
        _Float16* a2h = (_Float16*)(ws + NWS_A2H);
        _Float16* a2l = (_Float16*)(ws + NWS_A2L);
        _Float16* w2h = (_Float16*)(ws + NWS_W2H);
        _Float16* w2l = (_Float16*)(ws + NWS_W2L);
        _Float16* xh  = (_Float16*)(ws + NWS_X2);
        _Float16* xl  = (_Float16*)(ws + NWS_X2 + 16777216);
        float4* boxes = (float4*)(ws + NWS_BOXES);
        unsigned long long* keys  = (unsigned long long*)(ws + NWS_KEYS);
        unsigned long long* skeys = (unsigned long long*)(ws + NWS_SKEYS);
        int* hist = (int*)(ws + NWS_HIST);
        int* cur  = (int*)(ws + NWS_CUR);
        int* cnt  = (int*)(ws + NWS_CNT);
        int* base = (int*)(ws + NWS_BASE);
        _Float16* wbh = (_Float16*)(ws + NWS_SKEYS);           // dead before scatter writes skeys
        _Float16* wbl = (_Float16*)(ws + NWS_SKEYS + 65536);
        unsigned long long* msk = (unsigned long long*)(ws + NWS_A1H);   // 2 MB
        float4* cbox  = (float4*)(ws + NWS_A1L);
        float*  carea = (float*)(ws + NWS_A1L + 262144);
        unsigned long long* sk2 = keys;

        fused_prep_kernel<<<8269, 256, 0, stream>>>(
            feat, a1h, a1l, w1, w1h, w1l, w2, w2h, w2l,
            w_s, w_b, wbh, wbl, a2h, a2l, (int4*)(ws + NWS_HIST));
        conv_mfma_kernel<1024, true ><<<512, 512, 0, stream>>>(a1h, a1l, w1h, w1l, b1, a2h, a2l);
        conv_mfma_kernel< 512, false><<<512, 512, 0, stream>>>(a2h, a2l, w2h, w2l, b2, xh, xl);
        heads_mfma_kernel<<<128, 256, 0, stream>>>(xh, xl, wbh, wbl, b_s, b_b, boxes, keys, cnt, hist);
        scan_kernel<<<1, 256, 0, stream>>>(hist, base);
        scatter_kernel<<<576, 256, 0, stream>>>(keys, cnt, base, cur, skeys);
        sortb_kernel<<<NB, 256, 0, stream>>>(skeys, base, boxes, sk2, cbox, carea);
        mask_kernel<<<dim3(16, 16), 256, 0, stream>>>(cbox, carea, msk);
        walk_kernel<<<1, 256, 0, stream>>>(sk2, cnt, cbox, carea, msk, boxes, out);
    } else {
        float* x1 = (float*)(ws + WS_X1);
        float* x2 = (float*)(ws + WS_X2);
        float4* boxes = (float4*)(ws + WS_BOXES);
        unsigned long long* keys  = (unsigned long long*)(ws + WS_KEYS);
        unsigned long long* skeys = (unsigned long long*)(ws + WS_SKEYS);
        int* hist = (int*)(ws + WS_HIST);
        int* cur  = (int*)(ws + WS_CUR);
        int* cnt  = (int*)(ws + WS_CNT);
        int* base = (int*)(ws + WS_BASE);
        unsigned long long* msk = (unsigned long long*)(ws + WS_X1);
        float4* cbox  = (float4*)(ws + WS_X2);
        float*  carea = (float*)(ws + WS_X2 + 262144);
        unsigned long long* sk2 = keys;

        hipMemsetAsync(ws + WS_HIST, 0, (WS_CNT - WS_HIST) + 256, stream);
        conv3x3_kernel<1024, true,  true ><<<2048, 256, 0, stream>>>(feat, w1, b1, x1);
        conv3x3_kernel< 512, false, false><<<2048, 256, 0, stream>>>(x1,   w2, b2, x2);
        heads_decode_kernel<<<4096, 256, 0, stream>>>(x2, w_s, b_s, w_b, b_b, boxes, keys, cnt, hist);
        scan_kernel<<<1, 256, 0, stream>>>(hist, base);
        scatter_kernel<<<576, 256, 0, stream>>>(keys, cnt, base, cur, skeys);
        sortb_kernel<<<NB, 256, 0, stream>>>(skeys, base, boxes, sk2, cbox, carea);
        mask_kernel<<<dim3(16, 16), 256, 0, stream>>>(cbox, carea, msk);
        walk_kernel<<<1, 256, 0, stream>>>(sk2, cnt, cbox, carea, msk, boxes, out);
    }
}